// Round 12
// baseline (365.912 us; speedup 1.0000x reference)
//
#include <hip/hip_runtime.h>
#include <hip/hip_bf16.h>
#include <hip/hip_cooperative_groups.h>
#include <stdint.h>

namespace cg = cooperative_groups;

// ---------------------------------------------------------------------------
// SelfAttn: B=4, W=H=64, C=256, C2=128, N=W*H=4096.
// pq = raw q buffer viewed [128,4096]  (Q_rows[n,c] = q_flat[c*4096+n])
// pv = raw v buffer viewed [256,4096]
// energy = Qrm @ Krm^T (K=128), softmax over keys (fixed ref m=0),
// O[n,c] = sum_m P[n,m] V[m,c];  final[b,c*4096+n] = gamma*O/l + x.
//
// R11 post-mortem: fusing merge INTO attn made attn stream all K/V per block
// (FETCH 2x, attn 72->89us) for only ~11us of dispatch savings. Dispatch gaps
// are ~12-19us each, ~50-75us total across 4 kernels. R12: ONE cooperative
// kernel, grid 512x256 (exactly 2 blocks/CU resident), phases A prep-W ->
// B proj -> C attn (R10 ks-split, measured 72us) -> D merge, separated by
// grid.sync(). LDS unioned (34.8KB max). Fallback to 4-kernel R10 path if
// cooperative launch is rejected.
// ---------------------------------------------------------------------------

typedef __attribute__((ext_vector_type(8)))  short short8;   // 8 x bf16
typedef __attribute__((ext_vector_type(4)))  float f32x4;
typedef __attribute__((ext_vector_type(16))) float f32x16;
typedef __attribute__((ext_vector_type(4)))  unsigned short u16x4;

#define MFMA16 __builtin_amdgcn_mfma_f32_16x16x32_bf16
#define MFMA32 __builtin_amdgcn_mfma_f32_32x32x16_bf16

#define SMEM_BYTES 34816   // max(proj T 34816, attn Ps 18432, merge 33024)

__device__ __forceinline__ unsigned short f2bf(float f) {
    union { float f; uint32_t u; } v; v.f = f;
    return (unsigned short)((v.u + 0x8000u) >> 16);    // round-half-up
}
__device__ __forceinline__ float bf2f(unsigned short h) {
    union { uint32_t u; float f; } v; v.u = ((uint32_t)h) << 16;
    return v.f;
}
// packed f32x2 -> bf16x2 (v_cvt_pk_bf16_f32, RNE)
__device__ __forceinline__ uint32_t pkbf(float a, float b) {
    union { __hip_bfloat162 h; uint32_t u; } v;
    v.h = __float22bfloat162_rn(float2{a, b});
    return v.u;
}

// === Phase A: Wt[512][256] bf16 (transposed, fused qkv) + bias[512] f32 ====
__device__ __forceinline__ void phase_prep(
        int bid, int tid,
        const float* __restrict__ Wq, const float* __restrict__ bq,
        const float* __restrict__ Wk, const float* __restrict__ bk,
        const float* __restrict__ Wv, const float* __restrict__ bv,
        unsigned short* __restrict__ Wt, float* __restrict__ bias) {
    int g = bid * 256 + tid;
    int c = g & 255, d = g >> 8;
    float val;
    if (d < 128)      val = Wq[c * 128 + d];
    else if (d < 256) val = Wk[c * 128 + (d - 128)];
    else              val = Wv[c * 256 + (d - 256)];
    Wt[d * 256 + c] = f2bf(val);
    if (g < 512) {
        float bb;
        if (g < 128)      bb = bq[g];
        else if (g < 256) bb = bk[g - 128];
        else              bb = bv[g - 256];
        bias[g] = bb;
    }
}

// === Phase B: fused QKV projection (R10). 512 uniform blocks ===============
//   [0,128)   Q-kind -> Qrm [n][128] tiles
//   [128,256) K-kind -> Kp[c-chunk(8)][m(4096)][k(16)] packed
//   [256,512) V-kind -> Vp[m-chunk(256)][c(256)][k(16)] packed
__device__ __forceinline__ void phase_proj(
        char* smem, int bid, int tid,
        const float* __restrict__ x, const unsigned short* __restrict__ Wt,
        const float* __restrict__ bias,
        unsigned short* __restrict__ Qrm, unsigned short* __restrict__ Kp,
        unsigned short* __restrict__ Vp) {
    unsigned short* T = (unsigned short*)smem;         // [128][136]
    int wave = tid >> 6, lane = tid & 63;
    int l16 = lane & 15, quad = lane >> 4;

    int kind, b, a, vh = 0;
    if (bid < 256) { kind = bid >> 7; int s = bid & 127; b = s >> 5; a = s & 31; }
    else           { kind = 2; int s = bid - 256; vh = s >> 7; b = (s >> 5) & 3; a = s & 31; }

    short8 af[2][8];
    #pragma unroll
    for (int g = 0; g < 2; ++g) {
        int p_local = wave * 32 + g * 16 + l16;
        int pix = (kind == 2) ? (b * 4096 + a * 128 + p_local)
                              : (b * 4096 + a + 32 * p_local);
        const float* xr = x + (size_t)pix * 256;
        #pragma unroll
        for (int kk = 0; kk < 8; ++kk) {
            f32x4 u0 = *(const f32x4*)(xr + kk * 32 + quad * 8);
            f32x4 u1 = *(const f32x4*)(xr + kk * 32 + quad * 8 + 4);
            union { short8 s; uint32_t u[4]; } h;
            h.u[0] = pkbf(u0[0], u0[1]); h.u[1] = pkbf(u0[2], u0[3]);
            h.u[2] = pkbf(u1[0], u1[1]); h.u[3] = pkbf(u1[2], u1[3]);
            af[g][kk] = h.s;
        }
    }

    if (kind < 2) {
        int dbase = kind * 128;
        #pragma unroll 1
        for (int dt = 0; dt < 8; ++dt) {
            int d = dbase + dt * 16 + l16;
            float bval = bias[d];
            f32x4 acc0 = {0.f,0.f,0.f,0.f}, acc1 = {0.f,0.f,0.f,0.f};
            #pragma unroll
            for (int kk = 0; kk < 8; ++kk) {
                short8 wrow = *(const short8*)(Wt + d * 256 + kk * 32 + quad * 8);
                acc0 = MFMA16(af[0][kk], wrow, acc0, 0, 0, 0);
                acc1 = MFMA16(af[1][kk], wrow, acc1, 0, 0, 0);
            }
            #pragma unroll
            for (int g = 0; g < 2; ++g) {
                f32x4 acc = g ? acc1 : acc0;
                union { u16x4 v; uint32_t u[2]; } pk;
                pk.u[0] = pkbf(acc[0] + bval, acc[1] + bval);
                pk.u[1] = pkbf(acc[2] + bval, acc[3] + bval);
                *(u16x4*)(T + (dt * 16 + l16) * 136 + wave * 32 + g * 16 + quad * 4) = pk.v;
            }
        }
        __syncthreads();
        if (kind == 0) {
            unsigned short* ob = Qrm + (b << 19) + a * 128 * 128;
            #pragma unroll
            for (int it = 0; it < 8; ++it) {
                int ci = it * 256 + tid;
                int row = ci >> 4, cj = ci & 15;
                *(short8*)(ob + row * 128 + cj * 8) = *(const short8*)(T + row * 136 + cj * 8);
            }
        } else {
            unsigned short* kb = Kp + (b << 19);
            #pragma unroll
            for (int it = 0; it < 8; ++it) {
                int ci = it * 256 + tid;
                int row = ci >> 4, cj = ci & 15;
                *(short8*)(kb + (cj >> 1) * 65536 + (a * 128 + row) * 16 + (cj & 1) * 8)
                    = *(const short8*)(T + row * 136 + cj * 8);
            }
        }
    } else {
        #pragma unroll 1
        for (int dt = 0; dt < 8; ++dt) {
            int d = 256 + vh * 128 + dt * 16 + l16;
            f32x4 acc0 = {0.f,0.f,0.f,0.f}, acc1 = {0.f,0.f,0.f,0.f};
            #pragma unroll
            for (int kk = 0; kk < 8; ++kk) {
                short8 wrow = *(const short8*)(Wt + d * 256 + kk * 32 + quad * 8);
                acc0 = MFMA16(wrow, af[0][kk], acc0, 0, 0, 0);   // A=W, B=x -> D^T
                acc1 = MFMA16(wrow, af[1][kk], acc1, 0, 0, 0);
            }
            int dvl = dt * 16 + quad * 4;
            f32x4 bv4 = *(const f32x4*)(bias + 256 + vh * 128 + dvl);
            #pragma unroll
            for (int g = 0; g < 2; ++g) {
                f32x4 acc = g ? acc1 : acc0;
                union { u16x4 v; uint32_t u[2]; } pk;
                pk.u[0] = pkbf(acc[0] + bv4[0], acc[1] + bv4[1]);
                pk.u[1] = pkbf(acc[2] + bv4[2], acc[3] + bv4[3]);
                int p_local = wave * 32 + g * 16 + l16;
                *(u16x4*)(T + p_local * 136 + dvl) = pk.v;
            }
        }
        __syncthreads();
        unsigned short* vb = Vp + (b << 20);
        #pragma unroll
        for (int it = 0; it < 8; ++it) {
            int cid = it * 256 + tid;
            int c_local = cid >> 8, w = cid & 255;
            int p_local = c_local * 16 + (w >> 4);
            int chunk = (w >> 4) * 16 + vh * 8 + ((w & 15) >> 1);
            *(short8*)(vb + chunk * 4096 + (a * 8 + c_local) * 16 + (w & 1) * 8)
                = *(const short8*)(T + p_local * 136 + (w & 15) * 8);
        }
    }
}

// === Phase C: flash attention (R10, measured 72us) =========================
// 512 blocks = 64 qtiles x (4 b x 2 ks); 64 q/block, 64-key tiles x 32,
// 32x32x16 MFMA; packed-coalesced K/V direct loads; LDS = Ps dbuf only.
__device__ __forceinline__ void phase_attn(
        char* smem, int bid, int tid,
        const unsigned short* __restrict__ Qrm, const unsigned short* __restrict__ Kp,
        const unsigned short* __restrict__ Vp, unsigned short* __restrict__ Opart,
        float* __restrict__ Lpart) {
    unsigned short* Ps = (unsigned short*)smem;        // [2][64][72] u16

    int comb = bid & 7, qt = bid >> 3;                 // same (b,ks) -> same XCD
    int b = comb >> 1, ks = comb & 1;
    int wave = tid >> 6, lane = tid & 63;
    int l32 = lane & 31, half = lane >> 5;
    int mt = wave & 1, nt = wave >> 1;

    const unsigned short* Qb = Qrm + (b << 19);
    const unsigned short* Kb = Kp + (b << 19);
    const unsigned short* Vb = Vp + (b << 20);

    int q0 = qt * 64;

    short8 qf[8];                                      // B=Q for wave's 32 queries
    {
        const unsigned short* qrow = Qb + (q0 + nt * 32 + l32) * 128 + half * 8;
        #pragma unroll
        for (int kk = 0; kk < 8; ++kk) qf[kk] = *(const short8*)(qrow + kk * 16);
    }

    f32x16 O[2][2];                                    // [qtile][ctile]
    #pragma unroll
    for (int i = 0; i < 2; ++i)
        #pragma unroll
        for (int j = 0; j < 2; ++j)
            #pragma unroll
            for (int r = 0; r < 16; ++r) O[i][j][r] = 0.f;
    float l_run = 0.f;

    const int m_base = ks * 2048;
    const int chunk_base = ks * 128;

    int krow = (m_base + mt * 32 + l32) * 16 + half * 8;
    short8 kf[8];
    #pragma unroll
    for (int kk = 0; kk < 8; ++kk)
        kf[kk] = *(const short8*)(Kb + kk * 65536 + krow);
    short8 vfrag[2][4];
    #pragma unroll
    for (int c2 = 0; c2 < 2; ++c2)
        #pragma unroll
        for (int k2 = 0; k2 < 4; ++k2)
            vfrag[c2][k2] = *(const short8*)(Vp + (b << 20) + (chunk_base + k2) * 4096
                              + ((wave * 2 + c2) * 32 + l32) * 16 + half * 8);

    #pragma unroll 1
    for (int kt = 0; kt < 32; ++kt) {
        unsigned short* Pb = Ps + (kt & 1) * (64 * 72);

        // 1. S^T[m][n]: A=kf, B=qf; col n = l32, row m = (r&3)+8*(r>>2)+4*half
        f32x16 S;
        #pragma unroll
        for (int r = 0; r < 16; ++r) S[r] = 0.f;
        #pragma unroll
        for (int kk = 0; kk < 8; ++kk) S = MFMA32(kf[kk], qf[kk], S, 0, 0, 0);

        // 2. fixed-ref softmax: p = exp(S); pack -> Ps[buf]
        #pragma unroll
        for (int g = 0; g < 4; ++g) {
            float p0 = __expf(S[g * 4 + 0]), p1 = __expf(S[g * 4 + 1]);
            float p2 = __expf(S[g * 4 + 2]), p3 = __expf(S[g * 4 + 3]);
            l_run += (p0 + p1) + (p2 + p3);
            union { u16x4 v; uint32_t u[2]; } pk;
            pk.u[0] = pkbf(p0, p1); pk.u[1] = pkbf(p2, p3);
            *(u16x4*)(Pb + (nt * 32 + l32) * 72 + mt * 32 + g * 8 + half * 4) = pk.v;
        }

        __syncthreads();                               // 3. Ps[buf] ready

        if (kt < 31) {                                 // 4. kf prefetch
            int kr1 = (m_base + (kt + 1) * 64 + mt * 32 + l32) * 16 + half * 8;
            #pragma unroll
            for (int kk = 0; kk < 8; ++kk)
                kf[kk] = *(const short8*)(Kb + kk * 65536 + kr1);
        }

        // 5. PV: A = P rows (q), B = vfrag
        #pragma unroll
        for (int k2 = 0; k2 < 4; ++k2) {
            short8 pa0 = *(const short8*)(Pb + (l32) * 72 + k2 * 16 + half * 8);
            short8 pa1 = *(const short8*)(Pb + (32 + l32) * 72 + k2 * 16 + half * 8);
            O[0][0] = MFMA32(pa0, vfrag[0][k2], O[0][0], 0, 0, 0);
            O[0][1] = MFMA32(pa0, vfrag[1][k2], O[0][1], 0, 0, 0);
            O[1][0] = MFMA32(pa1, vfrag[0][k2], O[1][0], 0, 0, 0);
            O[1][1] = MFMA32(pa1, vfrag[1][k2], O[1][1], 0, 0, 0);
        }

        if (kt < 31) {                                 // 6. vfrag prefetch
            int ch1 = chunk_base + (kt + 1) * 4;
            #pragma unroll
            for (int c2 = 0; c2 < 2; ++c2)
                #pragma unroll
                for (int k2 = 0; k2 < 4; ++k2)
                    vfrag[c2][k2] = *(const short8*)(Vb + (ch1 + k2) * 4096
                                      + ((wave * 2 + c2) * 32 + l32) * 16 + half * 8);
        }
    }

    // epilogue: unnormalized O + per-query l partials
    l_run += __shfl_xor(l_run, 32);
    unsigned short* Op = Opart + ((size_t)(ks * 4 + b) << 20);
    #pragma unroll
    for (int q2 = 0; q2 < 2; ++q2)
        #pragma unroll
        for (int c2 = 0; c2 < 2; ++c2) {
            int c = (wave * 2 + c2) * 32 + l32;
            #pragma unroll
            for (int r = 0; r < 16; ++r) {
                int n = q0 + q2 * 32 + (r & 3) + 8 * (r >> 2) + 4 * half;
                Op[(size_t)n * 256 + c] = f2bf(O[q2][c2][r]);
            }
        }
    if (half == 0) {
        int n = q0 + nt * 32 + l32;
        Lpart[((ks * 2 + mt) * 4 + b) * 4096 + n] = l_run;
    }
}

// === Phase D: merge 2 key-splits, gamma*O/l + x, transpose =================
// 512 blocks: b = bid>>7, 32-row n-tile n0 = (bid&127)*32.
__device__ __forceinline__ void phase_merge(
        char* smem, int bid, int tid,
        const unsigned short* __restrict__ Opart, const float* __restrict__ Lpart,
        const float* __restrict__ x, const float* __restrict__ gamma,
        float* __restrict__ out) {
    float* tile = (float*)smem;                        // [32][257]
    float* wsm  = (float*)smem + 32 * 257;             // [32]
    int b  = bid >> 7;
    int n0 = (bid & 127) << 5;
    float g = gamma[0];
    if (tid < 32) {
        int n = n0 + tid;
        float L = 0.f;
        #pragma unroll
        for (int s = 0; s < 4; ++s) L += Lpart[(s * 4 + b) * 4096 + n];
        wsm[tid] = g / L;
    }
    __syncthreads();
    int nl1 = tid >> 5, cb1 = (tid & 31) * 8;
    const unsigned short* Op0 = Opart + ((size_t)b << 20);
    const unsigned short* Op1 = Opart + ((size_t)(4 + b) << 20);
    #pragma unroll
    for (int i = 0; i < 4; ++i) {
        int nl = i * 8 + nl1;
        size_t off = (size_t)(n0 + nl) * 256 + cb1;
        short8 o0 = *(const short8*)(Op0 + off);
        short8 o1 = *(const short8*)(Op1 + off);
        float w = wsm[nl];
        float* tr = tile + nl * 257 + cb1;
        #pragma unroll
        for (int e = 0; e < 8; ++e)
            tr[e] = (bf2f((unsigned short)o0[e]) + bf2f((unsigned short)o1[e])) * w;
    }
    __syncthreads();
    int cg2 = tid >> 3, nq = (tid & 7) * 4;
    #pragma unroll
    for (int it = 0; it < 8; ++it) {
        int c = it * 32 + cg2;
        size_t idx = ((size_t)b << 20) + (size_t)c * 4096 + n0 + nq;
        f32x4 xv = *(const f32x4*)(x + idx);
        f32x4 ov;
        #pragma unroll
        for (int e = 0; e < 4; ++e) ov[e] = tile[(nq + e) * 257 + c] + xv[e];
        *(f32x4*)(out + idx) = ov;
    }
}

// === Fused cooperative kernel ==============================================
__global__ void __launch_bounds__(256, 2) fused_all(
        const float* x, const float* Wq, const float* bq, const float* Wk,
        const float* bk, const float* Wv, const float* bv, const float* gamma,
        float* out, unsigned short* Wt, float* bias, unsigned short* Qrm,
        unsigned short* Kp, unsigned short* Vp, unsigned short* Opart,
        float* Lpart) {
    __shared__ __align__(16) char smem[SMEM_BYTES];
    cg::grid_group grid = cg::this_grid();
    int bid = blockIdx.x, tid = threadIdx.x;

    phase_prep(bid, tid, Wq, bq, Wk, bk, Wv, bv, Wt, bias);
    grid.sync();
    phase_proj(smem, bid, tid, x, Wt, bias, Qrm, Kp, Vp);
    grid.sync();
    phase_attn(smem, bid, tid, Qrm, Kp, Vp, Opart, Lpart);
    grid.sync();
    phase_merge(smem, bid, tid, Opart, Lpart, x, gamma, out);
}

// === Fallback standalone kernels (R10 path) ================================
__global__ void prep_w_k(const float* Wq, const float* bq, const float* Wk,
                         const float* bk, const float* Wv, const float* bv,
                         unsigned short* Wt, float* bias) {
    phase_prep(blockIdx.x, threadIdx.x, Wq, bq, Wk, bk, Wv, bv, Wt, bias);
}
__global__ __launch_bounds__(256) void proj_k(
        const float* x, const unsigned short* Wt, const float* bias,
        unsigned short* Qrm, unsigned short* Kp, unsigned short* Vp) {
    __shared__ __align__(16) char smem[SMEM_BYTES];
    phase_proj(smem, blockIdx.x, threadIdx.x, x, Wt, bias, Qrm, Kp, Vp);
}
__global__ __launch_bounds__(256, 2) void attn_k(
        const unsigned short* Qrm, const unsigned short* Kp,
        const unsigned short* Vp, unsigned short* Opart, float* Lpart) {
    __shared__ __align__(16) char smem[18432];
    phase_attn(smem, blockIdx.x, threadIdx.x, Qrm, Kp, Vp, Opart, Lpart);
}
__global__ __launch_bounds__(256) void merge_k(
        const unsigned short* Opart, const float* Lpart, const float* x,
        const float* gamma, float* out) {
    __shared__ __align__(16) char smem[33024];
    phase_merge(smem, blockIdx.x, threadIdx.x, Opart, Lpart, x, gamma, out);
}

// ---------------------------------------------------------------------------
extern "C" void kernel_launch(void* const* d_in, const int* in_sizes, int n_in,
                              void* d_out, int out_size, void* d_ws, size_t ws_size,
                              hipStream_t stream) {
    const float* x     = (const float*)d_in[0];
    const float* Wq    = (const float*)d_in[1];
    const float* bq    = (const float*)d_in[2];
    const float* Wk    = (const float*)d_in[3];
    const float* bk    = (const float*)d_in[4];
    const float* Wv    = (const float*)d_in[5];
    const float* bv    = (const float*)d_in[6];
    const float* gamma = (const float*)d_in[7];
    float* out = (float*)d_out;

    if (ws_size < 34080768u) return;   // need ~33 MB scratch

    char* ws = (char*)d_ws;
    unsigned short* Wt    = (unsigned short*)(ws);             //    262,144 B
    float*          bias  = (float*)        (ws +   262144);   //      2,048 B
    unsigned short* Qrm   = (unsigned short*)(ws +   264192);  //  4,194,304 B
    unsigned short* Kp    = (unsigned short*)(ws +  4458496);  //  4,194,304 B
    unsigned short* Vp    = (unsigned short*)(ws +  8652800);  //  8,388,608 B
    unsigned short* Opart = (unsigned short*)(ws + 17041408);  // 16,777,216 B
    float*          Lpart = (float*)        (ws + 33818624);   //    262,144 B

    void* args[] = { (void*)&x, (void*)&Wq, (void*)&bq, (void*)&Wk, (void*)&bk,
                     (void*)&Wv, (void*)&bv, (void*)&gamma, (void*)&out,
                     (void*)&Wt, (void*)&bias, (void*)&Qrm, (void*)&Kp,
                     (void*)&Vp, (void*)&Opart, (void*)&Lpart };
    hipError_t err = hipLaunchCooperativeKernel((const void*)fused_all,
                                                dim3(512), dim3(256),
                                                args, 0, stream);
    if (err != hipSuccess) {
        // fallback: 4-kernel R10 path (identical math)
        prep_w_k<<<512, 256, 0, stream>>>(Wq, bq, Wk, bk, Wv, bv, Wt, bias);
        proj_k  <<<512, 256, 0, stream>>>(x, Wt, bias, Qrm, Kp, Vp);
        attn_k  <<<512, 256, 0, stream>>>(Qrm, Kp, Vp, Opart, Lpart);
        merge_k <<<512, 256, 0, stream>>>(Opart, Lpart, x, gamma, out);
    }
}

// Round 13
// 172.520 us; speedup vs baseline: 2.1210x; 2.1210x over previous
//
#include <hip/hip_runtime.h>
#include <hip/hip_bf16.h>
#include <stdint.h>

// ---------------------------------------------------------------------------
// SelfAttn: B=4, W=H=64, C=256, C2=128, N=W*H=4096.
// pq = raw q buffer viewed [128,4096]  (Q_rows[n,c] = q_flat[c*4096+n])
// pv = raw v buffer viewed [256,4096]
// energy = Qrm @ Krm^T (K=128), softmax over keys (fixed ref m=0),
// O[n,c] = sum_m P[n,m] V[m,c];  final[b,c*4096+n] = gamma*O/l + x.
//
// R12 post-mortem: cooperative grid.sync() costs ~60us each (284us fused vs
// ~105us of phase work) -> dead lever. R13: revert to R10 (best, 175.4us);
// software-pipeline attn: per iteration compute QK+softmax(kt+1) alongside
// PV(kt) with ONE barrier -- softmax VALU (43k cyc/SIMD) now has 24 MFMA32
// of independent work to hide under. Ps dbuf makes the rotation safe.
// ---------------------------------------------------------------------------

typedef __attribute__((ext_vector_type(8)))  short short8;   // 8 x bf16
typedef __attribute__((ext_vector_type(4)))  float f32x4;
typedef __attribute__((ext_vector_type(16))) float f32x16;
typedef __attribute__((ext_vector_type(4)))  unsigned short u16x4;

#define MFMA16 __builtin_amdgcn_mfma_f32_16x16x32_bf16
#define MFMA32 __builtin_amdgcn_mfma_f32_32x32x16_bf16

__device__ __forceinline__ unsigned short f2bf(float f) {
    union { float f; uint32_t u; } v; v.f = f;
    return (unsigned short)((v.u + 0x8000u) >> 16);    // round-half-up
}
__device__ __forceinline__ float bf2f(unsigned short h) {
    union { uint32_t u; float f; } v; v.u = ((uint32_t)h) << 16;
    return v.f;
}
// packed f32x2 -> bf16x2 (v_cvt_pk_bf16_f32, RNE)
__device__ __forceinline__ uint32_t pkbf(float a, float b) {
    union { __hip_bfloat162 h; uint32_t u; } v;
    v.h = __float22bfloat162_rn(float2{a, b});
    return v.u;
}

// --- K1: Wt[512][256] bf16 (transposed, fused qkv) + bias[512] f32 ---------
__global__ void prep_w(const float* __restrict__ Wq, const float* __restrict__ bq,
                       const float* __restrict__ Wk, const float* __restrict__ bk,
                       const float* __restrict__ Wv, const float* __restrict__ bv,
                       unsigned short* __restrict__ Wt, float* __restrict__ bias) {
    int g = blockIdx.x * 256 + threadIdx.x;
    int c = g & 255, d = g >> 8;
    float val;
    if (d < 128)      val = Wq[c * 128 + d];
    else if (d < 256) val = Wk[c * 128 + (d - 128)];
    else              val = Wv[c * 256 + (d - 256)];
    Wt[d * 256 + c] = f2bf(val);
    if (g < 512) {
        float bb;
        if (g < 128)      bb = bq[g];
        else if (g < 256) bb = bk[g - 128];
        else              bb = bv[g - 256];
        bias[g] = bb;
    }
}

// --- K2: fused QKV projection. 512 uniform blocks (R10):
//   [0,128)   Q-kind -> Qrm [n][128] tiles
//   [128,256) K-kind -> Kp[c-chunk(8)][m(4096)][k(16)] packed
//   [256,512) V-kind -> Vp[m-chunk(256)][c(256)][k(16)] packed
__global__ __launch_bounds__(256) void proj(
        const float* __restrict__ x, const unsigned short* __restrict__ Wt,
        const float* __restrict__ bias,
        unsigned short* __restrict__ Qrm, unsigned short* __restrict__ Kp,
        unsigned short* __restrict__ Vp) {
    __shared__ unsigned short T[128 * 136];
    int bid = blockIdx.x;
    int tid = threadIdx.x;
    int wave = tid >> 6, lane = tid & 63;
    int l16 = lane & 15, quad = lane >> 4;

    int kind, b, a, vh = 0;
    if (bid < 256) { kind = bid >> 7; int s = bid & 127; b = s >> 5; a = s & 31; }
    else           { kind = 2; int s = bid - 256; vh = s >> 7; b = (s >> 5) & 3; a = s & 31; }

    short8 af[2][8];
    #pragma unroll
    for (int g = 0; g < 2; ++g) {
        int p_local = wave * 32 + g * 16 + l16;
        int pix = (kind == 2) ? (b * 4096 + a * 128 + p_local)
                              : (b * 4096 + a + 32 * p_local);
        const float* xr = x + (size_t)pix * 256;
        #pragma unroll
        for (int kk = 0; kk < 8; ++kk) {
            f32x4 u0 = *(const f32x4*)(xr + kk * 32 + quad * 8);
            f32x4 u1 = *(const f32x4*)(xr + kk * 32 + quad * 8 + 4);
            union { short8 s; uint32_t u[4]; } h;
            h.u[0] = pkbf(u0[0], u0[1]); h.u[1] = pkbf(u0[2], u0[3]);
            h.u[2] = pkbf(u1[0], u1[1]); h.u[3] = pkbf(u1[2], u1[3]);
            af[g][kk] = h.s;
        }
    }

    if (kind < 2) {
        int dbase = kind * 128;
        #pragma unroll 1
        for (int dt = 0; dt < 8; ++dt) {
            int d = dbase + dt * 16 + l16;
            float bval = bias[d];
            f32x4 acc0 = {0.f,0.f,0.f,0.f}, acc1 = {0.f,0.f,0.f,0.f};
            #pragma unroll
            for (int kk = 0; kk < 8; ++kk) {
                short8 wrow = *(const short8*)(Wt + d * 256 + kk * 32 + quad * 8);
                acc0 = MFMA16(af[0][kk], wrow, acc0, 0, 0, 0);
                acc1 = MFMA16(af[1][kk], wrow, acc1, 0, 0, 0);
            }
            #pragma unroll
            for (int g = 0; g < 2; ++g) {
                f32x4 acc = g ? acc1 : acc0;
                union { u16x4 v; uint32_t u[2]; } pk;
                pk.u[0] = pkbf(acc[0] + bval, acc[1] + bval);
                pk.u[1] = pkbf(acc[2] + bval, acc[3] + bval);
                *(u16x4*)(T + (dt * 16 + l16) * 136 + wave * 32 + g * 16 + quad * 4) = pk.v;
            }
        }
        __syncthreads();
        if (kind == 0) {
            unsigned short* ob = Qrm + (b << 19) + a * 128 * 128;
            #pragma unroll
            for (int it = 0; it < 8; ++it) {
                int ci = it * 256 + tid;
                int row = ci >> 4, cj = ci & 15;
                *(short8*)(ob + row * 128 + cj * 8) = *(const short8*)(T + row * 136 + cj * 8);
            }
        } else {
            unsigned short* kb = Kp + (b << 19);
            #pragma unroll
            for (int it = 0; it < 8; ++it) {
                int ci = it * 256 + tid;
                int row = ci >> 4, cj = ci & 15;
                *(short8*)(kb + (cj >> 1) * 65536 + (a * 128 + row) * 16 + (cj & 1) * 8)
                    = *(const short8*)(T + row * 136 + cj * 8);
            }
        }
    } else {
        #pragma unroll 1
        for (int dt = 0; dt < 8; ++dt) {
            int d = 256 + vh * 128 + dt * 16 + l16;
            f32x4 acc0 = {0.f,0.f,0.f,0.f}, acc1 = {0.f,0.f,0.f,0.f};
            #pragma unroll
            for (int kk = 0; kk < 8; ++kk) {
                short8 wrow = *(const short8*)(Wt + d * 256 + kk * 32 + quad * 8);
                acc0 = MFMA16(wrow, af[0][kk], acc0, 0, 0, 0);   // A=W, B=x -> D^T
                acc1 = MFMA16(wrow, af[1][kk], acc1, 0, 0, 0);
            }
            int dvl = dt * 16 + quad * 4;
            f32x4 bv4 = *(const f32x4*)(bias + 256 + vh * 128 + dvl);
            #pragma unroll
            for (int g = 0; g < 2; ++g) {
                f32x4 acc = g ? acc1 : acc0;
                union { u16x4 v; uint32_t u[2]; } pk;
                pk.u[0] = pkbf(acc[0] + bv4[0], acc[1] + bv4[1]);
                pk.u[1] = pkbf(acc[2] + bv4[2], acc[3] + bv4[3]);
                int p_local = wave * 32 + g * 16 + l16;
                *(u16x4*)(T + p_local * 136 + dvl) = pk.v;
            }
        }
        __syncthreads();
        unsigned short* vb = Vp + (b << 20);
        #pragma unroll
        for (int it = 0; it < 8; ++it) {
            int cid = it * 256 + tid;
            int c_local = cid >> 8, w = cid & 255;
            int p_local = c_local * 16 + (w >> 4);
            int chunk = (w >> 4) * 16 + vh * 8 + ((w & 15) >> 1);
            *(short8*)(vb + chunk * 4096 + (a * 8 + c_local) * 16 + (w & 1) * 8)
                = *(const short8*)(T + p_local * 136 + (w & 15) * 8);
        }
    }
}

// --- K3: flash attention, software-pipelined. ------------------------------
// grid 512 = 64 qtiles x (4 b x 2 ks); 64 q/block, 64-key tiles x 32,
// 32x32x16 MFMA, packed-coalesced K/V direct loads, Ps dbuf.
// Loop rotated: iteration kt runs QK+softmax(kt+1) next to PV(kt) -> the
// softmax VALU overlaps the MFMA pipe. ONE barrier per iteration.
__global__ __launch_bounds__(256, 2) void attn(
        const unsigned short* __restrict__ Qrm, const unsigned short* __restrict__ Kp,
        const unsigned short* __restrict__ Vp, unsigned short* __restrict__ Opart,
        float* __restrict__ Lpart) {
    __shared__ unsigned short Ps[2 * 64 * 72];         // P [q=64][m=64 +pad], x2

    int bid = blockIdx.x;
    int comb = bid & 7, qt = bid >> 3;                 // same (b,ks) -> same XCD
    int b = comb >> 1, ks = comb & 1;
    int tid = threadIdx.x, wave = tid >> 6, lane = tid & 63;
    int l32 = lane & 31, half = lane >> 5;
    int mt = wave & 1, nt = wave >> 1;

    const unsigned short* Qb = Qrm + (b << 19);
    const unsigned short* Kb = Kp + (b << 19);
    const unsigned short* Vb = Vp + (b << 20);

    int q0 = qt * 64;

    short8 qf[8];                                      // B=Q for wave's 32 queries
    {
        const unsigned short* qrow = Qb + (q0 + nt * 32 + l32) * 128 + half * 8;
        #pragma unroll
        for (int kk = 0; kk < 8; ++kk) qf[kk] = *(const short8*)(qrow + kk * 16);
    }

    f32x16 O[2][2];                                    // [qtile][ctile]
    #pragma unroll
    for (int i = 0; i < 2; ++i)
        #pragma unroll
        for (int j = 0; j < 2; ++j)
            #pragma unroll
            for (int r = 0; r < 16; ++r) O[i][j][r] = 0.f;
    float l_run = 0.f;                                 // own-half partial only

    const int m_base = ks * 2048;
    const int chunk_base = ks * 128;                   // m_base>>4
    const int kbase = (m_base + mt * 32 + l32) * 16 + half * 8;

    // ---- prologue: K(0) -> S(0) -> softmax -> Ps[0]; then kf <- K(1) ------
    short8 kf[8];
    #pragma unroll
    for (int kk = 0; kk < 8; ++kk)
        kf[kk] = *(const short8*)(Kb + kk * 65536 + kbase);
    short8 vfrag[2][4];                                // V(0)
    #pragma unroll
    for (int c2 = 0; c2 < 2; ++c2)
        #pragma unroll
        for (int k2 = 0; k2 < 4; ++k2)
            vfrag[c2][k2] = *(const short8*)(Vb + (chunk_base + k2) * 4096
                              + ((wave * 2 + c2) * 32 + l32) * 16 + half * 8);
    {
        f32x16 S;
        #pragma unroll
        for (int r = 0; r < 16; ++r) S[r] = 0.f;
        #pragma unroll
        for (int kk = 0; kk < 8; ++kk) S = MFMA32(kf[kk], qf[kk], S, 0, 0, 0);
        #pragma unroll
        for (int g = 0; g < 4; ++g) {
            float p0 = __expf(S[g * 4 + 0]), p1 = __expf(S[g * 4 + 1]);
            float p2 = __expf(S[g * 4 + 2]), p3 = __expf(S[g * 4 + 3]);
            l_run += (p0 + p1) + (p2 + p3);
            union { u16x4 v; uint32_t u[2]; } pk;
            pk.u[0] = pkbf(p0, p1); pk.u[1] = pkbf(p2, p3);
            *(u16x4*)(Ps + (nt * 32 + l32) * 72 + mt * 32 + g * 8 + half * 4) = pk.v;
        }
        #pragma unroll
        for (int kk = 0; kk < 8; ++kk)                 // kf <- K(1)
            kf[kk] = *(const short8*)(Kb + kk * 65536 + 64 * 16 + kbase);
    }

    #pragma unroll 1
    for (int kt = 0; kt < 32; ++kt) {
        __syncthreads();   // Ps[kt&1] visible; PV(kt-1) done -> other buf free

        // QK + softmax for kt+1 (independent of PV(kt) below)
        if (kt < 31) {
            f32x16 S;
            #pragma unroll
            for (int r = 0; r < 16; ++r) S[r] = 0.f;
            #pragma unroll
            for (int kk = 0; kk < 8; ++kk) S = MFMA32(kf[kk], qf[kk], S, 0, 0, 0);
            if (kt < 30) {                             // kf <- K(kt+2)
                int kr = (kt + 2) * 64 * 16 + kbase;
                #pragma unroll
                for (int kk = 0; kk < 8; ++kk)
                    kf[kk] = *(const short8*)(Kb + kk * 65536 + kr);
            }
            unsigned short* Pn = Ps + ((kt + 1) & 1) * (64 * 72);
            #pragma unroll
            for (int g = 0; g < 4; ++g) {
                float p0 = __expf(S[g * 4 + 0]), p1 = __expf(S[g * 4 + 1]);
                float p2 = __expf(S[g * 4 + 2]), p3 = __expf(S[g * 4 + 3]);
                l_run += (p0 + p1) + (p2 + p3);
                union { u16x4 v; uint32_t u[2]; } pk;
                pk.u[0] = pkbf(p0, p1); pk.u[1] = pkbf(p2, p3);
                *(u16x4*)(Pn + (nt * 32 + l32) * 72 + mt * 32 + g * 8 + half * 4) = pk.v;
            }
        }

        // PV(kt): A = P rows (q) from Ps[kt&1], B = vfrag(kt)
        unsigned short* Pb = Ps + (kt & 1) * (64 * 72);
        #pragma unroll
        for (int k2 = 0; k2 < 4; ++k2) {
            short8 pa0 = *(const short8*)(Pb + (l32) * 72 + k2 * 16 + half * 8);
            short8 pa1 = *(const short8*)(Pb + (32 + l32) * 72 + k2 * 16 + half * 8);
            O[0][0] = MFMA32(pa0, vfrag[0][k2], O[0][0], 0, 0, 0);
            O[0][1] = MFMA32(pa0, vfrag[1][k2], O[0][1], 0, 0, 0);
            O[1][0] = MFMA32(pa1, vfrag[0][k2], O[1][0], 0, 0, 0);
            O[1][1] = MFMA32(pa1, vfrag[1][k2], O[1][1], 0, 0, 0);
        }

        if (kt < 31) {                                 // vfrag <- V(kt+1)
            int ch1 = chunk_base + (kt + 1) * 4;
            #pragma unroll
            for (int c2 = 0; c2 < 2; ++c2)
                #pragma unroll
                for (int k2 = 0; k2 < 4; ++k2)
                    vfrag[c2][k2] = *(const short8*)(Vb + (ch1 + k2) * 4096
                                      + ((wave * 2 + c2) * 32 + l32) * 16 + half * 8);
        }
    }

    // epilogue: unnormalized O + per-query l partials (cross-half sum here)
    l_run += __shfl_xor(l_run, 32);
    unsigned short* Op = Opart + ((size_t)(ks * 4 + b) << 20);
    #pragma unroll
    for (int q2 = 0; q2 < 2; ++q2)
        #pragma unroll
        for (int c2 = 0; c2 < 2; ++c2) {
            int c = (wave * 2 + c2) * 32 + l32;
            #pragma unroll
            for (int r = 0; r < 16; ++r) {
                int n = q0 + q2 * 32 + (r & 3) + 8 * (r >> 2) + 4 * half;
                Op[(size_t)n * 256 + c] = f2bf(O[q2][c2][r]);
            }
        }
    if (half == 0) {
        int n = q0 + nt * 32 + l32;
        Lpart[((ks * 2 + mt) * 4 + b) * 4096 + n] = l_run;
    }
}

// --- K4: merge 2 key-splits, gamma*O/l + x, transpose [n,c]->[c,n] ---------
__global__ __launch_bounds__(256) void merge_out(
        const unsigned short* __restrict__ Opart, const float* __restrict__ Lpart,
        const float* __restrict__ x, const float* __restrict__ gamma,
        float* __restrict__ out) {
    __shared__ float tile[64 * 257];                   // [n=64][c=256 +pad]
    __shared__ float wsm[64];
    int b  = blockIdx.x >> 6;
    int n0 = (blockIdx.x & 63) << 6;
    int tid = threadIdx.x;
    float g = gamma[0];
    if (tid < 64) {
        int n = n0 + tid;
        float L = 0.f;
        #pragma unroll
        for (int s = 0; s < 4; ++s) L += Lpart[(s * 4 + b) * 4096 + n];
        wsm[tid] = g / L;
    }
    __syncthreads();
    int nl1 = tid >> 5, cb1 = (tid & 31) * 8;
    const unsigned short* Op0 = Opart + ((size_t)b << 20);
    const unsigned short* Op1 = Opart + ((size_t)(4 + b) << 20);
    #pragma unroll
    for (int i = 0; i < 8; ++i) {
        int nl = i * 8 + nl1;
        size_t off = (size_t)(n0 + nl) * 256 + cb1;
        short8 o0 = *(const short8*)(Op0 + off);
        short8 o1 = *(const short8*)(Op1 + off);
        float w = wsm[nl];
        float* tr = tile + nl * 257 + cb1;
        #pragma unroll
        for (int e = 0; e < 8; ++e)
            tr[e] = (bf2f((unsigned short)o0[e]) + bf2f((unsigned short)o1[e])) * w;
    }
    __syncthreads();
    int cg = tid >> 4, nq = (tid & 15) * 4;
    #pragma unroll
    for (int it = 0; it < 16; ++it) {
        int c = it * 16 + cg;
        size_t idx = ((size_t)b << 20) + (size_t)c * 4096 + n0 + nq;
        f32x4 xv = *(const f32x4*)(x + idx);
        f32x4 ov;
        #pragma unroll
        for (int e = 0; e < 4; ++e) ov[e] = tile[(nq + e) * 257 + c] + xv[e];
        *(f32x4*)(out + idx) = ov;
    }
}

// ---------------------------------------------------------------------------
extern "C" void kernel_launch(void* const* d_in, const int* in_sizes, int n_in,
                              void* d_out, int out_size, void* d_ws, size_t ws_size,
                              hipStream_t stream) {
    const float* x     = (const float*)d_in[0];
    const float* Wq    = (const float*)d_in[1];
    const float* bq    = (const float*)d_in[2];
    const float* Wk    = (const float*)d_in[3];
    const float* bk    = (const float*)d_in[4];
    const float* Wv    = (const float*)d_in[5];
    const float* bv    = (const float*)d_in[6];
    const float* gamma = (const float*)d_in[7];
    float* out = (float*)d_out;

    if (ws_size < 34080768u) return;   // need ~33 MB scratch

    char* ws = (char*)d_ws;
    unsigned short* Wt    = (unsigned short*)(ws);             //    262,144 B
    float*          bias  = (float*)        (ws +   262144);   //      2,048 B
    unsigned short* Qrm   = (unsigned short*)(ws +   264192);  //  4,194,304 B
    unsigned short* Kp    = (unsigned short*)(ws +  4458496);  //  4,194,304 B
    unsigned short* Vp    = (unsigned short*)(ws +  8652800);  //  8,388,608 B
    unsigned short* Opart = (unsigned short*)(ws + 17041408);  // 16,777,216 B
    float*          Lpart = (float*)        (ws + 33818624);   //    262,144 B

    prep_w   <<<512, 256, 0, stream>>>(Wq, bq, Wk, bk, Wv, bv, Wt, bias);
    proj     <<<512, 256, 0, stream>>>(x, Wt, bias, Qrm, Kp, Vp);
    attn     <<<512, 256, 0, stream>>>(Qrm, Kp, Vp, Opart, Lpart);
    merge_out<<<256, 256, 0, stream>>>(Opart, Lpart, x, gamma, out);
}